// Round 11
// baseline (388.455 us; speedup 1.0000x reference)
//
#include <hip/hip_runtime.h>

#define HSZ 50        // real hidden units
#define TSZ 512       // timesteps
#define NS  2         // independent batch-streams per workgroup
#define NB  4         // batches per stream -> 8 per wg -> 256 wgs (1/CU)
#define KPAD 72       // hlds row stride in f16 (144 B, 16B-aligned)
#define GNS 260       // gl batch stride in dwords (u*4+g layout, +4 pad)

typedef _Float16 half8   __attribute__((ext_vector_type(8)));
typedef float    floatx4 __attribute__((ext_vector_type(4)));

// sigmoid/tanh via exp+rcp, robust at extremes (proven R4-R10, absmax ~1e-3)
__device__ __forceinline__ float fast_sig(float x) {
    return __builtin_amdgcn_rcpf(1.0f + __expf(-x));
}
__device__ __forceinline__ float fast_tanh(float x) {
    return fmaf(-2.0f, __builtin_amdgcn_rcpf(1.0f + __expf(2.0f * x)), 1.0f);
}

// R10 machinery (K-augmented MFMA, gate-interleaved repack, 1 barrier/step)
// x 2 independent streams per workgroup. The two streams' per-step chains are
// interleaved in the SAME wave's instruction stream, so each stage's latency
// (B-read, MFMA, repack round-trip, trans) is deterministically hidden under
// the other stream's issue, and one barrier serves both streams. A-fragments
// (weights) are shared. 256 wgs = 1 wg/CU, 1 wave/SIMD; waves_per_eu(1,1)
// hands RA the full register file.
__global__ __launch_bounds__(256) __attribute__((amdgpu_waves_per_eu(1, 1)))
void lstm_dual(const float* __restrict__ x,
               const float* __restrict__ W_ih,
               const float* __restrict__ W_hh,
               const float* __restrict__ b_ih,
               const float* __restrict__ b_hh,
               const float* __restrict__ W_lin,
               const float* __restrict__ b_lin,
               float* __restrict__ out)
{
    __shared__ float xs[TSZ][NS * NB];                       // x^T      (16 KB)
    __shared__ __align__(16) float gl[NS][4][NB * GNS];      // repack (33.3 KB)
    __shared__ __align__(16) _Float16 hlds[NS][2][16][KPAD]; // aug-h^T (9.2 KB)

    const int tid = threadIdx.x;
    const int w   = tid >> 6;        // wave id 0..3 -> unit group [16w,16w+16)
    const int ln  = tid & 63;        // lane
    const int n   = ln & 15;         // MFMA column
    const int q   = ln >> 4;         // quad
    const int na  = ln >> 4;         // activation batch (0..3)
    const int ua  = ln & 15;         // activation unit offset (0..15)
    const int b0  = blockIdx.x * NS * NB;

    // --- stage x transposed: global [b][t] -> LDS [t][b], 8 batches ---
    const float* xg = x + (size_t)b0 * TSZ;
    for (int i = tid; i < NS * NB * TSZ; i += 256)
        xs[i & (TSZ - 1)][i >> 9] = xg[i];
    // --- init h buffers: zero except k==50 slot = 1.0 (all 4 buffers) ---
    for (int i = tid; i < NS * 2 * 16 * KPAD; i += 256)
        ((_Float16*)hlds)[i] = (i % KPAD == 50) ? (_Float16)1.0f : (_Float16)0.0f;

    // --- A fragments (shared by both streams): A[m=16w+n][k], augmented:
    //     k<50 -> W_hh ; k==50 -> b_ih+b_hh ; k==51 -> W_ih ; else 0.
    const int uA = 16 * w + n;
    half8 af[4][2];
#pragma unroll
    for (int g = 0; g < 4; ++g) {
        const int row = g * HSZ + uA;
        const bool rok = (uA < HSZ);
#pragma unroll
        for (int kt = 0; kt < 2; ++kt) {
#pragma unroll
            for (int j = 0; j < 8; ++j) {
                const int k = kt * 32 + q * 8 + j;
                float v = 0.0f;
                if (rok) {
                    if (k < HSZ)      v = W_hh[row * HSZ + k];
                    else if (k == 50) v = b_ih[row] + b_hh[row];
                    else if (k == 51) v = W_ih[row];
                }
                af[g][kt][j] = (_Float16)v;
            }
        }
    }

    float c2[NS] = {0.0f, 0.0f};     // lane-local cell state per stream
    __syncthreads();                 // xs + hlds base fill ready
    if (tid < NS * NB)               // x_0 into buffer 0's aug slots
        hlds[tid >> 2][0][tid & 3][51] = (_Float16)xs[0][tid];
    __syncthreads();

    const floatx4 zero4 = {0.0f, 0.0f, 0.0f, 0.0f};
    const int kdst = 16 * w + ua;    // this lane's h destination row in k
    const bool hwr = (kdst != 50) && (kdst != 51);   // keep aug slots intact

#pragma unroll 2
    for (int t = 0; t < TSZ; ++t) {
        const int rb = t & 1, wb = rb ^ 1;

        // B fragments for both streams (issue together, waits overlap).
        half8 bf[NS][2];
#pragma unroll
        for (int s = 0; s < NS; ++s) {
            bf[s][0] = *(const half8*)&hlds[s][rb][n][q * 8];
            bf[s][1] = *(const half8*)&hlds[s][rb][n][32 + q * 8];
        }
        // Next step's x into the write buffers' aug slots (wave s -> stream s).
        if (w < NS && ua == 15)
            hlds[w][wb][na][51] = (_Float16)xs[(t + 1) & (TSZ - 1)][4 * w + na];

        // MFMAs: 2 streams x 4 gates x 2 k-frags; C-input literal zero (K-aug).
        floatx4 acc[NS][4];
#pragma unroll
        for (int s = 0; s < NS; ++s)
#pragma unroll
            for (int g = 0; g < 4; ++g) {
                acc[s][g] = __builtin_amdgcn_mfma_f32_16x16x32_f16(af[g][0], bf[s][0], zero4,     0, 0, 0);
                acc[s][g] = __builtin_amdgcn_mfma_f32_16x16x32_f16(af[g][1], bf[s][1], acc[s][g], 0, 0, 0);
            }

        // Wave-private repack, gate-interleaved {i,f,g,o} per (unit,batch).
        if (n < NB) {
#pragma unroll
            for (int s = 0; s < NS; ++s)
#pragma unroll
                for (int r = 0; r < 4; ++r) {
                    const floatx4 v = {acc[s][0][r], acc[s][1][r], acc[s][2][r], acc[s][3][r]};
                    *(floatx4*)&gl[s][w][n * GNS + (4 * q + r) * 4] = v;
                }
        }
        // Consume: one b128 per stream gives this lane's 4 gate preacts;
        // stream 0's trans fills stream 1's read latency and vice versa.
#pragma unroll
        for (int s = 0; s < NS; ++s) {
            const floatx4 pre = *(const floatx4*)&gl[s][w][na * GNS + ua * 4];
            const float si = fast_sig (pre[0]);
            const float sf = fast_sig (pre[1]);
            const float sg = fast_tanh(pre[2]);
            const float so = fast_sig (pre[3]);
            c2[s] = fmaf(sf, c2[s], si * sg);
            const float h = so * fast_tanh(c2[s]);
            if (hwr)
                hlds[s][wb][na][kdst] = (_Float16)h;
        }
        __syncthreads();             // h(t) of both streams visible
    }

    // --- epilogue: wave s emits stream s's 4 outputs. TSZ even -> buffer 0.
    if (w < NS && ln < NB) {
        float acc = b_lin[0];
        for (int u = 0; u < HSZ; ++u)
            acc = fmaf((float)hlds[w][0][ln][u], W_lin[u], acc);
        out[(size_t)b0 + 4 * w + ln] = acc;
    }
}

extern "C" void kernel_launch(void* const* d_in, const int* in_sizes, int n_in,
                              void* d_out, int out_size, void* d_ws, size_t ws_size,
                              hipStream_t stream) {
    const float* x     = (const float*)d_in[0];
    const float* W_ih  = (const float*)d_in[1];
    const float* W_hh  = (const float*)d_in[2];
    const float* b_ih  = (const float*)d_in[3];
    const float* b_hh  = (const float*)d_in[4];
    const float* W_lin = (const float*)d_in[5];
    const float* b_lin = (const float*)d_in[6];
    float* outp = (float*)d_out;

    const int B = in_sizes[0] / TSZ;   // 2048 -> 256 wgs x (2 streams x 4)
    hipLaunchKernelGGL(lstm_dual, dim3(B / (NS * NB)), dim3(256), 0, stream,
                       x, W_ih, W_hh, b_ih, b_hh, W_lin, b_lin, outp);
}

// Round 12
// 377.062 us; speedup vs baseline: 1.0302x; 1.0302x over previous
//
#include <hip/hip_runtime.h>

#define HSZ 50        // real hidden units
#define TSZ 512       // timesteps
#define NB  4         // batches per workgroup -> 512 wgs (2/CU)
#define KPAD 72       // hlds row stride in f16 (144 B, 16B-aligned rows)

typedef _Float16 half8   __attribute__((ext_vector_type(8)));
typedef float    floatx4 __attribute__((ext_vector_type(4)));

// sigmoid/tanh via exp+rcp, robust at extremes (proven R4-R11, absmax ~1e-3)
__device__ __forceinline__ float fast_sig(float x) {
    return __builtin_amdgcn_rcpf(1.0f + __expf(-x));
}
__device__ __forceinline__ float fast_tanh(float x) {
    return fmaf(-2.0f, __builtin_amdgcn_rcpf(1.0f + __expf(2.0f * x)), 1.0f);
}

__device__ __forceinline__ float bperm(int bidx, float v) {
    return __int_as_float(__builtin_amdgcn_ds_bpermute(bidx, __float_as_int(v)));
}

// R10 skeleton (4 waves x 4-batch stream, K-augmented MFMA, 1 barrier/step)
// with the two serial LDS stages removed from the chain:
// (1) gate exchange via 16 ds_bpermute + cndmask selects (crossbar; no LDS
//     round-trip, no bank conflicts, no barrier) -- consumer (na,ua) pulls
//     acc[g][ua&3] from wave-local producer lane 16*(ua>>2)+na.
// (2) K-aug slots patched in-register: after loading bf1, q==2 lanes insert
//     1.0 at k=50 and (f16)x_t at k=51 -- no per-step x ds_write, no h-write
//     masking; hlds carries pure h (pad units stay exactly 0: zero A-rows ->
//     i=f=o=0.5, g=0 -> c=0, h=0).
__global__ __launch_bounds__(256) __attribute__((amdgpu_waves_per_eu(2, 2)))
void lstm_bperm(const float* __restrict__ x,
                const float* __restrict__ W_ih,
                const float* __restrict__ W_hh,
                const float* __restrict__ b_ih,
                const float* __restrict__ b_hh,
                const float* __restrict__ W_lin,
                const float* __restrict__ b_lin,
                float* __restrict__ out)
{
    __shared__ float xs[TSZ][NB];                         // x^T [t][n]   (8 KB)
    __shared__ __align__(16) _Float16 hlds[2][16][KPAD];  // h^T dbuf   (4.5 KB)

    const int tid = threadIdx.x;
    const int w   = tid >> 6;        // wave id 0..3 -> unit group [16w,16w+16)
    const int ln  = tid & 63;        // lane
    const int n   = ln & 15;         // MFMA column
    const int q   = ln >> 4;         // quad
    const int na  = ln >> 4;         // activation batch (0..3)
    const int ua  = ln & 15;         // activation unit offset (0..15)
    const int b0  = blockIdx.x * NB;

    // --- stage x transposed: global [b][t] -> LDS [t][b] (coalesced) ---
    const float* xg = x + (size_t)b0 * TSZ;
    for (int i = tid; i < NB * TSZ; i += 256)
        xs[i & (TSZ - 1)][i >> 9] = xg[i];
    // --- zero h buffers (h0 = 0; rows 4..15 and pad units stay 0) ---
    for (int i = tid; i < 2 * 16 * KPAD; i += 256)
        ((_Float16*)hlds)[i] = (_Float16)0.0f;

    // --- A fragments: lane holds A[m=16w+n][k=kt*32+q*8+j], augmented:
    //     k<50 -> W_hh ; k==50 -> b_ih+b_hh ; k==51 -> W_ih ; else 0.
    const int uA = 16 * w + n;
    half8 af[4][2];
#pragma unroll
    for (int g = 0; g < 4; ++g) {
        const int row = g * HSZ + uA;
        const bool rok = (uA < HSZ);
#pragma unroll
        for (int kt = 0; kt < 2; ++kt) {
#pragma unroll
            for (int j = 0; j < 8; ++j) {
                const int k = kt * 32 + q * 8 + j;
                float v = 0.0f;
                if (rok) {
                    if (k < HSZ)      v = W_hh[row * HSZ + k];
                    else if (k == 50) v = b_ih[row] + b_hh[row];
                    else if (k == 51) v = W_ih[row];
                }
                af[g][kt][j] = (_Float16)v;
            }
        }
    }

    // --- exchange constants: producer lane + register-select masks ---
    const int  bidx  = 4 * (16 * (ua >> 2) + na);   // ds_bpermute byte index
    const bool selr0 = (ua & 1) != 0;               // element select bits
    const bool selr1 = (ua & 2) != 0;
    const int  kdst  = 16 * w + ua;                 // this lane's h row in k

    float c = 0.0f;                  // lane-local cell state (batch na, unit kdst)
    __syncthreads();                 // xs + hlds ready

    const floatx4 zero4 = {0.0f, 0.0f, 0.0f, 0.0f};

#pragma unroll 2
    for (int t = 0; t < TSZ; ++t) {
        const int rb = t & 1, wb = rb ^ 1;

        // B fragments: hlds[rb][n][k-contiguous]; patch aug slots in-register.
        const half8 bf0 = *(const half8*)&hlds[rb][n][q * 8];
        half8 bf1 = *(const half8*)&hlds[rb][n][32 + q * 8];
        const float xv = xs[t][n & 3];
        if (q == 2) {                 // k=50 -> 1.0, k=51 -> x_t (elements 2,3)
            bf1[2] = (_Float16)1.0f;
            bf1[3] = (_Float16)xv;
        }

        // 4 gate MFMAs, C-input literal zero (bias/x via K-aug).
        floatx4 acc[4];
#pragma unroll
        for (int g = 0; g < 4; ++g) {
            acc[g] = __builtin_amdgcn_mfma_f32_16x16x32_f16(af[g][0], bf0, zero4,  0, 0, 0);
            acc[g] = __builtin_amdgcn_mfma_f32_16x16x32_f16(af[g][1], bf1, acc[g], 0, 0, 0);
        }

        // In-register gate exchange: pull acc[g][r] from producer lane, select
        // r = ua&3. 16 bpermutes (crossbar) + 12 cndmasks, no barrier.
        float pre[4];
#pragma unroll
        for (int g = 0; g < 4; ++g) {
            const float t0 = bperm(bidx, acc[g][0]);
            const float t1 = bperm(bidx, acc[g][1]);
            const float t2 = bperm(bidx, acc[g][2]);
            const float t3 = bperm(bidx, acc[g][3]);
            const float s01 = selr0 ? t1 : t0;
            const float s23 = selr0 ? t3 : t2;
            pre[g] = selr1 ? s23 : s01;
        }

        // 10 trans, lane-local state update for (batch na, unit kdst).
        const float si = fast_sig (pre[0]);
        const float sf = fast_sig (pre[1]);
        const float sg = fast_tanh(pre[2]);
        const float so = fast_sig (pre[3]);
        c = fmaf(sf, c, si * sg);
        const float h = so * fast_tanh(c);

        hlds[wb][na][kdst] = (_Float16)h;   // pad units write 0: harmless
        __syncthreads();             // h(t) visible for next step's B-read
    }

    // --- epilogue: out[b0+n'] = b_lin + sum_u h_T[u]*W_lin[u]; TSZ even -> buf 0
    if (w == 0 && ln < NB) {
        float acc = b_lin[0];
        for (int u = 0; u < HSZ; ++u)
            acc = fmaf((float)hlds[0][ln][u], W_lin[u], acc);
        out[(size_t)b0 + ln] = acc;
    }
}

extern "C" void kernel_launch(void* const* d_in, const int* in_sizes, int n_in,
                              void* d_out, int out_size, void* d_ws, size_t ws_size,
                              hipStream_t stream) {
    const float* x     = (const float*)d_in[0];
    const float* W_ih  = (const float*)d_in[1];
    const float* W_hh  = (const float*)d_in[2];
    const float* b_ih  = (const float*)d_in[3];
    const float* b_hh  = (const float*)d_in[4];
    const float* W_lin = (const float*)d_in[5];
    const float* b_lin = (const float*)d_in[6];
    float* outp = (float*)d_out;

    const int B = in_sizes[0] / TSZ;   // 2048 -> 512 workgroups of 4 batches
    hipLaunchKernelGGL(lstm_bperm, dim3(B / NB), dim3(256), 0, stream,
                       x, W_ih, W_hh, b_ih, b_hh, W_lin, b_lin, outp);
}

// Round 15
// 323.392 us; speedup vs baseline: 1.2012x; 1.1660x over previous
//
#include <hip/hip_runtime.h>

#define HSZ 50        // real hidden units
#define TSZ 512       // timesteps
#define NB  4         // batches per workgroup -> 512 wgs (2/CU)
#define KPAD 72       // hlds row stride in f16 (144 B, 16B-aligned rows)
#define GNS 260       // gl batch stride in dwords (u*4+g layout, +4 pad)
#define LOG2E 1.44269504f

typedef _Float16 half8   __attribute__((ext_vector_type(8)));
typedef float    floatx4 __attribute__((ext_vector_type(4)));

// Activations on pre-scaled preacts (rows scaled by LOG2E / 2*LOG2E at load):
// sig(y)  with x =   LOG2E*y :  rcp(1 + exp2(-x))
// tanh(y) with x = 2*LOG2E*y :  1 - 2*rcp(1 + exp2(x))
// Native v_exp_f32 IS exp2 -> no multiply before any transcendental.
__device__ __forceinline__ float sig_x(float x) {
    return __builtin_amdgcn_rcpf(1.0f + __builtin_amdgcn_exp2f(-x));
}
__device__ __forceinline__ float tanh_x(float x) {
    return fmaf(-2.0f, __builtin_amdgcn_rcpf(1.0f + __builtin_amdgcn_exp2f(x)), 1.0f);
}

// R10 champion skeleton (4 waves x 4-batch stream, K-augmented MFMA,
// gate-interleaved LDS repack, 1 barrier/step) consolidated with the two
// proven cuts: (1) R12's in-register aug patch -- q==2 lanes insert 1.0 at
// k=50 and (f16)x_t at k=51 after the B-load, so hlds carries pure h, no
// per-step x ds_write, no masked h-write; (2) exp2 pre-scaling folded into
// the A rows so every sigmoid/tanh starts directly at native v_exp_f32.
__global__ __launch_bounds__(256) __attribute__((amdgpu_waves_per_eu(2, 2)))
void lstm_kaug2(const float* __restrict__ x,
                const float* __restrict__ W_ih,
                const float* __restrict__ W_hh,
                const float* __restrict__ b_ih,
                const float* __restrict__ b_hh,
                const float* __restrict__ W_lin,
                const float* __restrict__ b_lin,
                float* __restrict__ out)
{
    __shared__ float xs[TSZ][NB];                         // x^T [t][n]   (8 KB)
    __shared__ __align__(16) float gl[4][NB * GNS];       // [w][n*260+u*4+g]
    __shared__ __align__(16) _Float16 hlds[2][16][KPAD];  // h^T dbuf   (4.5 KB)

    const int tid = threadIdx.x;
    const int w   = tid >> 6;        // wave id 0..3 -> unit group [16w,16w+16)
    const int ln  = tid & 63;        // lane
    const int n   = ln & 15;         // MFMA column
    const int q   = ln >> 4;         // quad
    const int na  = ln >> 4;         // activation batch (0..3)
    const int ua  = ln & 15;         // activation unit offset (0..15)
    const int b0  = blockIdx.x * NB;

    // --- stage x transposed: global [b][t] -> LDS [t][b] (coalesced) ---
    const float* xg = x + (size_t)b0 * TSZ;
    for (int i = tid; i < NB * TSZ; i += 256)
        xs[i & (TSZ - 1)][i >> 9] = xg[i];
    // --- zero h buffers (pure h now; h0 = 0, pad rows stay 0) ---
    for (int i = tid; i < 2 * 16 * KPAD; i += 256)
        ((_Float16*)hlds)[i] = (_Float16)0.0f;

    // --- A fragments: lane holds A[m=16w+n][k=kt*32+q*8+j], augmented and
    //     exp2-pre-scaled: rows of gate g scaled by LOG2E (g!=2) or 2*LOG2E.
    //     k<50 -> W_hh ; k==50 -> b_ih+b_hh ; k==51 -> W_ih ; else 0.
    const int uA = 16 * w + n;
    half8 af[4][2];
#pragma unroll
    for (int g = 0; g < 4; ++g) {
        const int row = g * HSZ + uA;
        const bool rok = (uA < HSZ);
        const float scl = (g == 2) ? (2.0f * LOG2E) : LOG2E;
#pragma unroll
        for (int kt = 0; kt < 2; ++kt) {
#pragma unroll
            for (int j = 0; j < 8; ++j) {
                const int k = kt * 32 + q * 8 + j;
                float v = 0.0f;
                if (rok) {
                    if (k < HSZ)      v = W_hh[row * HSZ + k];
                    else if (k == 50) v = b_ih[row] + b_hh[row];
                    else if (k == 51) v = W_ih[row];
                }
                af[g][kt][j] = (_Float16)(v * scl);
            }
        }
    }

    float c = 0.0f;                  // lane-local cell state (batch na, unit 16w+ua)
    __syncthreads();                 // xs + hlds ready

    const floatx4 zero4 = {0.0f, 0.0f, 0.0f, 0.0f};
    const int kdst = 16 * w + ua;    // this lane's h destination row in k

#pragma unroll 2
    for (int t = 0; t < TSZ; ++t) {
        const int rb = t & 1, wb = rb ^ 1;

        // B fragments: hlds[rb][n][k-contiguous]; patch aug slots in-register
        // (proven in R12): k=50 -> 1.0, k=51 -> x_t (bf1 elements 2,3 at q==2).
        const half8 bf0 = *(const half8*)&hlds[rb][n][q * 8];
        half8 bf1 = *(const half8*)&hlds[rb][n][32 + q * 8];
        const float xv = xs[t][n & 3];
        if (q == 2) {
            bf1[2] = (_Float16)1.0f;
            bf1[3] = (_Float16)xv;
        }

        // 4 gate MFMAs, C-input literal zero (bias/x via K-aug).
        floatx4 acc[4];
#pragma unroll
        for (int g = 0; g < 4; ++g) {
            acc[g] = __builtin_amdgcn_mfma_f32_16x16x32_f16(af[g][0], bf0, zero4,  0, 0, 0);
            acc[g] = __builtin_amdgcn_mfma_f32_16x16x32_f16(af[g][1], bf1, acc[g], 0, 0, 0);
        }

        // Wave-private repack, gate-interleaved: lane (q, n<4) owns all 4
        // gates of units 4q+r -> b128 {i,f,g,o} to gl[w][n*260 + (4q+r)*4].
        if (n < NB) {
#pragma unroll
            for (int r = 0; r < 4; ++r) {
                const floatx4 v = {acc[0][r], acc[1][r], acc[2][r], acc[3][r]};
                *(floatx4*)&gl[w][n * GNS + (4 * q + r) * 4] = v;
            }
        }
        // Consumer: ONE b128 read gives this lane's 4 pre-scaled gate preacts.
        const floatx4 pre = *(const floatx4*)&gl[w][na * GNS + ua * 4];

        // Activations straight into native exp2 (no pre-multiplies).
        const float si = sig_x (pre[0]);
        const float sf = sig_x (pre[1]);
        const float sg = tanh_x(pre[2]);
        const float so = sig_x (pre[3]);
        c = fmaf(sf, c, si * sg);
        const float h = so * tanh_x(2.0f * LOG2E * c);

        hlds[wb][na][kdst] = (_Float16)h;   // pad units write 0: harmless
        __syncthreads();             // h(t) visible for next step's B-read
    }

    // --- epilogue: out[b0+n'] = b_lin + sum_u h_T[u]*W_lin[u]; TSZ even -> buf 0
    if (w == 0 && ln < NB) {
        float acc = b_lin[0];
        for (int u = 0; u < HSZ; ++u)
            acc = fmaf((float)hlds[0][ln][u], W_lin[u], acc);
        out[(size_t)b0 + ln] = acc;
    }
}

extern "C" void kernel_launch(void* const* d_in, const int* in_sizes, int n_in,
                              void* d_out, int out_size, void* d_ws, size_t ws_size,
                              hipStream_t stream) {
    const float* x     = (const float*)d_in[0];
    const float* W_ih  = (const float*)d_in[1];
    const float* W_hh  = (const float*)d_in[2];
    const float* b_ih  = (const float*)d_in[3];
    const float* b_hh  = (const float*)d_in[4];
    const float* W_lin = (const float*)d_in[5];
    const float* b_lin = (const float*)d_in[6];
    float* outp = (float*)d_out;

    const int B = in_sizes[0] / TSZ;   // 2048 -> 512 workgroups of 4 batches
    hipLaunchKernelGGL(lstm_kaug2, dim3(B / NB), dim3(256), 0, stream,
                       x, W_ih, W_hh, b_ih, b_hh, W_lin, b_lin, outp);
}